// Round 14
// baseline (31.244 us; speedup 1.0000x reference)
//
#include <hip/hip_runtime.h>
#include <math.h>

#define S 256
#define HD 768
#define RR 256
#define NSPAN 2020
#define BB 8

typedef __attribute__((ext_vector_type(8))) short bf16x8;
typedef __attribute__((ext_vector_type(4))) float f32x4;

__device__ inline ushort f2bf(float x) {
    union { float f; unsigned u; } v; v.f = x;
    unsigned r = v.u + 0x7FFF + ((v.u >> 16) & 1);
    return (ushort)(r >> 16);
}

// =============== k_pre: fused hmean(96) | cvtW(144) | prep(512) | EW(9) ===============
// Long-latency tasks get low block IDs so they dispatch first.
__global__ __launch_bounds__(256) void k_pre(const float* __restrict__ H,
                                             const float* __restrict__ w_attn,
                                             const float* __restrict__ b_attn,
                                             const float* __restrict__ mask,
                                             const float* __restrict__ Wspan,
                                             const float* __restrict__ W_width,
                                             ushort* __restrict__ Hb,
                                             float* __restrict__ logits,
                                             ushort* __restrict__ Wt,
                                             float* __restrict__ hmean,
                                             float* __restrict__ EW) {
    __shared__ __align__(16) char smem[16640];
    int bid = blockIdx.x;
    int tid = threadIdx.x;

    if (bid < 96) {
        // ---- hmean: 4 independent accumulators, fully unrolled ----
        float (*red)[64] = (float(*)[64])smem;
        float* msum = (float*)(smem + 1024);
        int b = bid & 7, hb = bid >> 3;
        int sg = tid >> 6, hl = tid & 63;
        int h = hb * 64 + hl;
        const float* Hbase = H + (size_t)b * S * HD + h;
        const float* mbase = mask + b * S;
        float a0 = 0.f, a1 = 0.f, a2 = 0.f, a3 = 0.f;
        #pragma unroll
        for (int s2 = 0; s2 < S; s2 += 16) {
            int s = s2 + sg;
            a0 += Hbase[(size_t)(s)      * HD] * mbase[s];
            a1 += Hbase[(size_t)(s + 4)  * HD] * mbase[s + 4];
            a2 += Hbase[(size_t)(s + 8)  * HD] * mbase[s + 8];
            a3 += Hbase[(size_t)(s + 12) * HD] * mbase[s + 12];
        }
        float acc = (a0 + a1) + (a2 + a3);
        float mv = mbase[tid];
        for (int off = 32; off; off >>= 1) mv += __shfl_down(mv, off);
        if (hl == 0) msum[sg] = mv;
        red[sg][hl] = acc;
        __syncthreads();
        if (sg == 0) {
            float ms = msum[0] + msum[1] + msum[2] + msum[3];
            float len = ms < 1.f ? 1.f : ms;
            hmean[b * HD + h] = (red[0][hl] + red[1][hl] + red[2][hl] + red[3][hl]) / len;
        }
    } else if (bid < 240) {
        // ---- cvtW: W_span[0:2304] -> Wt[n][h] bf16 transposed ----
        float (*tile)[65] = (float(*)[65])smem;
        int idx = bid - 96;
        int hb = idx % 12, rb = (idx / 12) & 3, c = idx / 48;
        for (int e = tid; e < 4096; e += 256) {
            int hl = e >> 6, rl = e & 63;
            tile[hl][rl] = Wspan[(size_t)(c * 768 + hb * 64 + hl) * 256 + rb * 64 + rl];
        }
        __syncthreads();
        for (int e = tid; e < 4096; e += 256) {
            int rl = e >> 6, hl = e & 63;
            Wt[(size_t)(c * 256 + rb * 64 + rl) * 768 + hb * 64 + hl] = f2bf(tile[hl][rl]);
        }
    } else if (bid < 752) {
        // ---- prep: H -> bf16 + logits (4 rows/block, 1 wave each) ----
        int pb = bid - 240;
        int wv = tid >> 6, lane = tid & 63;
        int row = pb * 4 + wv;
        const float4* h4 = (const float4*)(H + (size_t)row * HD);
        const float4* w4 = (const float4*)w_attn;
        float acc = 0.f;
        #pragma unroll
        for (int k = 0; k < 3; ++k) {
            float4 a = h4[k * 64 + lane];
            float4 w = w4[k * 64 + lane];
            acc += a.x * w.x + a.y * w.y + a.z * w.z + a.w * w.w;
            ushort4 o;
            o.x = f2bf(a.x); o.y = f2bf(a.y); o.z = f2bf(a.z); o.w = f2bf(a.w);
            *(ushort4*)(Hb + (size_t)row * HD + k * 256 + lane * 4) = o;
        }
        for (int off = 32; off; off >>= 1) acc += __shfl_down(acc, off);
        if (lane == 0) logits[row] = acc + b_attn[0];
    } else {
        // ---- EW[w][r] ----
        int w = bid - 752;
        int r = tid;
        float acc = 0.f;
        for (int k = 0; k < 32; ++k)
            acc += W_width[w * 32 + k] * Wspan[(size_t)(2304 + k) * RR + r];
        EW[w * RR + r] = acc;
    }
}

// =============== k_mid: GEMM 64x128, 2-phase dbuf gload_lds (192 blk) | null (64 blk) ===============
// Per buffer (24 KB): A region rows 0..63 at 0, B region rows 0..127 at +8192.
// Linear LDS dest + inverse-swizzled global source (XOR involution, rule #21);
// all issue regions are 8-row aligned so ck = (lane&7)^(lane>>3) everywhere.
__global__ __launch_bounds__(256) void k_mid(const ushort* __restrict__ Hb,
                                             const ushort* __restrict__ Wt,
                                             float* __restrict__ P,
                                             const float* __restrict__ hmean,
                                             const float* __restrict__ W_nasp,
                                             const float* __restrict__ b_nasp,
                                             const float* __restrict__ W_nopn,
                                             const float* __restrict__ b_nopn,
                                             float* __restrict__ out_nasp,
                                             float* __restrict__ out_nopn) {
    __shared__ __align__(16) char smem[49152];
    int bid = blockIdx.x;
    int tid = threadIdx.x;

    if (bid < 192) {
        char* lds = smem;
        int mt = bid & 31, nt = bid >> 5;          // mt 0..31, nt 0..5
        int m0 = mt * 64, n0 = nt * 128;
        int wv = tid >> 6, lane = tid & 63;
        int wm = (wv >> 1) * 32, wn = (wv & 1) * 64;

        int ck8 = ((lane & 7) ^ (lane >> 3)) * 8;  // swizzled source chunk (elems)
        int r8 = lane >> 3;                        // row-within-8 of this lane

        auto STAGE = [&](int buf, int k0) {
            char* dst = lds + buf * 24576;
            #pragma unroll
            for (int i = 0; i < 6; ++i) {
                int issue = wv * 6 + i;            // 0..23, wave-uniform
                if (issue < 8) {
                    int row = issue * 8 + r8;      // A rows 0..63
                    __builtin_amdgcn_global_load_lds(
                        (const __attribute__((address_space(1))) void*)(Hb + (size_t)(m0 + row) * HD + k0 + ck8),
                        (__attribute__((address_space(3))) void*)(dst + issue * 1024), 16, 0, 0);
                } else {
                    int row = (issue - 8) * 8 + r8; // B rows 0..127
                    __builtin_amdgcn_global_load_lds(
                        (const __attribute__((address_space(1))) void*)(Wt + (size_t)(n0 + row) * HD + k0 + ck8),
                        (__attribute__((address_space(3))) void*)(dst + 8192 + (issue - 8) * 1024), 16, 0, 0);
                }
            }
        };

        f32x4 acc[2][4] = {};

        STAGE(0, 0);
        __syncthreads();                       // tile 0 resident
        int cur = 0;
        #pragma unroll 1
        for (int t = 0; t < 12; ++t) {
            if (t + 1 < 12) STAGE(cur ^ 1, (t + 1) * 64);   // prefetch next tile
            char* cb = lds + cur * 24576;
            #pragma unroll
            for (int ks = 0; ks < 2; ++ks) {
                int kb = ks * 64 + ((lane >> 4) * 16);
                bf16x8 af[2], bfr[4];
                #pragma unroll
                for (int f = 0; f < 2; ++f) {
                    int ar = wm + f * 16 + (lane & 15);
                    af[f] = *(const bf16x8*)(cb + ar * 128 + (kb ^ ((ar & 7) << 4)));
                }
                #pragma unroll
                for (int j = 0; j < 4; ++j) {
                    int br = wn + j * 16 + (lane & 15);
                    bfr[j] = *(const bf16x8*)(cb + 8192 + br * 128 + (kb ^ ((br & 7) << 4)));
                }
                #pragma unroll
                for (int f = 0; f < 2; ++f)
                    #pragma unroll
                    for (int j = 0; j < 4; ++j)
                        acc[f][j] = __builtin_amdgcn_mfma_f32_16x16x32_bf16(af[f], bfr[j], acc[f][j], 0, 0, 0);
            }
            __syncthreads();   // drains vmcnt(0): next tile landed; cur reads done
            cur ^= 1;
        }

        #pragma unroll
        for (int f = 0; f < 2; ++f) {
            #pragma unroll
            for (int j = 0; j < 4; ++j) {
                int col = n0 + wn + j * 16 + (lane & 15);
                size_t pb = (size_t)(col >> 8) * 524288 + (col & 255);
                #pragma unroll
                for (int rg = 0; rg < 4; ++rg) {
                    int row = m0 + wm + f * 16 + (lane >> 4) * 4 + rg;
                    P[pb + (size_t)row * 256] = acc[f][j][rg];
                }
            }
        }
    } else {
        // ---- null heads: 64 blocks ----
        float* hm = (float*)smem;
        float (*ra)[32] = (float(*)[32])(smem + 4096);
        float (*ro)[32] = (float(*)[32])(smem + 5120);
        int idx = bid - 192;
        int b = idx >> 3, rc = idx & 7;
        int c = tid & 31, hc = tid >> 5;
        int r = rc * 32 + c;
        for (int h = tid; h < HD; h += 256) hm[h] = hmean[b * HD + h];
        __syncthreads();
        float a = 0.f, o = 0.f;
        for (int h = hc * 96; h < hc * 96 + 96; ++h) {
            float x = hm[h];
            a += x * W_nasp[(size_t)h * RR + r];
            o += x * W_nopn[(size_t)h * RR + r];
        }
        ra[hc][c] = a; ro[hc][c] = o;
        __syncthreads();
        if (tid < 32) {
            float sa = 0.f, so = 0.f;
            #pragma unroll
            for (int u = 0; u < 8; ++u) { sa += ra[u][tid]; so += ro[u][tid]; }
            int rr = rc * 32 + tid;
            out_nasp[b * RR + rr] = tanhf(sa + b_nasp[rr]);
            out_nopn[b * RR + rr] = tanhf(so + b_nopn[rr]);
        }
    }
}

// =============== k_span4: 1-D grid 2048, XCD-aligned swizzle; float4 per thread ===============
__global__ __launch_bounds__(64) void k_span4(const float* __restrict__ logits,
                                              const float* __restrict__ P,
                                              const float* __restrict__ EW,
                                              const float* __restrict__ b_span,
                                              const float* __restrict__ w_asp,
                                              const float* __restrict__ b_asp,
                                              const float* __restrict__ w_opn,
                                              const float* __restrict__ b_opn,
                                              float* __restrict__ out_repr,
                                              float* __restrict__ out_asp,
                                              float* __restrict__ out_opn) {
    // bijective XCD swizzle (2048 % 8 == 0): XCD x serves batch x's P slice.
    int bid = blockIdx.x;
    int id = (bid & 7) * 256 + (bid >> 3);
    int b = id >> 8;
    int start = id & 255;
    int nw = 256 - start; if (nw > 8) nw = 8;
    int t = threadIdx.x;          // 0..63, cols 4t..4t+3

    int nbase;
    if (start <= 248) nbase = start * 8;
    else { int tt = start - 249; nbase = 1992 + 7 * tt - (tt * (tt - 1)) / 2; }

    float E[8], inv[8];
    {
        float lg[8];
        float M = -INFINITY;
        #pragma unroll
        for (int l = 0; l < 8; ++l) {
            lg[l] = (l < nw) ? logits[b * S + start + l] : -INFINITY;
            M = fmaxf(M, lg[l]);
        }
        float run = 0.f;
        #pragma unroll
        for (int l = 0; l < 8; ++l) {
            E[l] = (l < nw) ? __expf(lg[l] - M) : 0.f;
            run += E[l];
            inv[l] = 1.f / run;
        }
    }

    size_t rb = ((size_t)b * S + start) * 64 + t;
    const f32x4* P04 = (const f32x4*)P;
    const f32x4* P14 = (const f32x4*)(P + 524288);
    const f32x4* P24 = (const f32x4*)(P + 1048576);

    f32x4 p0 = P04[rb];
    f32x4 bs = ((const f32x4*)b_span)[t];
    f32x4 wa = ((const f32x4*)w_asp)[t];
    f32x4 wo = ((const f32x4*)w_opn)[t];
    f32x4 num = {0.f, 0.f, 0.f, 0.f};
    float pa[8], po[8];

    #pragma unroll
    for (int j = 0; j < 8; ++j) {
        // speculative loads for j >= nw stay inside d_ws (safe, unused)
        f32x4 p2 = P24[rb + (size_t)j * 64];
        f32x4 p1 = P14[rb + (size_t)j * 64];
        f32x4 ewj = ((const f32x4*)EW)[(j + 1) * 64 + t];
        num += E[j] * p2;
        f32x4 pre = p0 + p1 + num * inv[j] + ewj + bs;
        f32x4 v;
        v[0] = fmaxf(pre[0], 0.f);
        v[1] = fmaxf(pre[1], 0.f);
        v[2] = fmaxf(pre[2], 0.f);
        v[3] = fmaxf(pre[3], 0.f);
        if (j < nw)
            *(f32x4*)(out_repr + ((size_t)b * NSPAN + nbase + j) * RR + t * 4) = v;
        pa[j] = v[0] * wa[0] + v[1] * wa[1] + v[2] * wa[2] + v[3] * wa[3];
        po[j] = v[0] * wo[0] + v[1] * wo[1] + v[2] * wo[2] + v[3] * wo[3];
    }

    #pragma unroll
    for (int j = 0; j < 8; ++j) {
        if (j < nw) {
            float a = pa[j], o = po[j];
            #pragma unroll
            for (int off = 32; off; off >>= 1) {
                a += __shfl_down(a, off);
                o += __shfl_down(o, off);
            }
            if (t == 0) {
                size_t oi = (size_t)b * NSPAN + nbase + j;
                out_asp[oi] = a + b_asp[0];
                out_opn[oi] = o + b_opn[0];
            }
        }
    }
}

extern "C" void kernel_launch(void* const* d_in, const int* in_sizes, int n_in,
                              void* d_out, int out_size, void* d_ws, size_t ws_size,
                              hipStream_t stream) {
    const float* H       = (const float*)d_in[0];
    const float* mask    = (const float*)d_in[1];
    const float* W_width = (const float*)d_in[2];
    const float* w_attn  = (const float*)d_in[3];
    const float* b_attn  = (const float*)d_in[4];
    const float* W_span  = (const float*)d_in[5];
    const float* b_span  = (const float*)d_in[6];
    const float* w_asp   = (const float*)d_in[7];
    const float* b_asp   = (const float*)d_in[8];
    const float* w_opn   = (const float*)d_in[9];
    const float* b_opn   = (const float*)d_in[10];
    const float* W_nasp  = (const float*)d_in[11];
    const float* b_nasp  = (const float*)d_in[12];
    const float* W_nopn  = (const float*)d_in[13];
    const float* b_nopn  = (const float*)d_in[14];

    float* out  = (float*)d_out;
    float* repr = out;
    float* asp  = out + (size_t)BB * NSPAN * RR;
    float* opn  = asp + (size_t)BB * NSPAN;
    float* nasp = opn + (size_t)BB * NSPAN;
    float* nopn = nasp + (size_t)BB * RR;

    float* ws     = (float*)d_ws;
    float* logits = ws;                 // 2048
    float* hmean  = ws + 2048;          // 6144
    float* EW     = ws + 8192;          // 2304
    float* P      = ws + 10496;         // 3 * 524288 fp32
    ushort* Hb    = (ushort*)(P + 1572864);     // 2048*768 bf16
    ushort* Wt    = Hb + (size_t)2048 * 768;    // 768*768 bf16

    k_pre<<<dim3(761), dim3(256), 0, stream>>>(H, w_attn, b_attn, mask, W_span, W_width,
                                               Hb, logits, Wt, hmean, EW);
    k_mid<<<dim3(256), dim3(256), 0, stream>>>(Hb, Wt, P, hmean,
                                               W_nasp, b_nasp, W_nopn, b_nopn, nasp, nopn);
    k_span4<<<dim3(BB * S), dim3(64), 0, stream>>>(logits, P, EW, b_span, w_asp, b_asp,
                                                   w_opn, b_opn, repr, asp, opn);
}

// Round 15
// 29.609 us; speedup vs baseline: 1.0552x; 1.0552x over previous
//
#include <hip/hip_runtime.h>
#include <math.h>

#define S 256
#define HD 768
#define RR 256
#define NSPAN 2020
#define BB 8

typedef __attribute__((ext_vector_type(8))) short bf16x8;
typedef __attribute__((ext_vector_type(4))) float f32x4;

__device__ inline ushort f2bf(float x) {
    union { float f; unsigned u; } v; v.f = x;
    unsigned r = v.u + 0x7FFF + ((v.u >> 16) & 1);
    return (ushort)(r >> 16);
}

// =============== k_pre: fused hmean(96) | cvtW(144) | prep(512) | EW(9) ===============
// Long-latency tasks get low block IDs so they dispatch first.
__global__ __launch_bounds__(256) void k_pre(const float* __restrict__ H,
                                             const float* __restrict__ w_attn,
                                             const float* __restrict__ b_attn,
                                             const float* __restrict__ mask,
                                             const float* __restrict__ Wspan,
                                             const float* __restrict__ W_width,
                                             ushort* __restrict__ Hb,
                                             float* __restrict__ logits,
                                             ushort* __restrict__ Wt,
                                             float* __restrict__ hmean,
                                             float* __restrict__ EW) {
    __shared__ __align__(16) char smem[16640];
    int bid = blockIdx.x;
    int tid = threadIdx.x;

    if (bid < 96) {
        // ---- hmean: 4 independent accumulators, fully unrolled ----
        float (*red)[64] = (float(*)[64])smem;
        float* msum = (float*)(smem + 1024);
        int b = bid & 7, hb = bid >> 3;
        int sg = tid >> 6, hl = tid & 63;
        int h = hb * 64 + hl;
        const float* Hbase = H + (size_t)b * S * HD + h;
        const float* mbase = mask + b * S;
        float a0 = 0.f, a1 = 0.f, a2 = 0.f, a3 = 0.f;
        #pragma unroll
        for (int s2 = 0; s2 < S; s2 += 16) {
            int s = s2 + sg;
            a0 += Hbase[(size_t)(s)      * HD] * mbase[s];
            a1 += Hbase[(size_t)(s + 4)  * HD] * mbase[s + 4];
            a2 += Hbase[(size_t)(s + 8)  * HD] * mbase[s + 8];
            a3 += Hbase[(size_t)(s + 12) * HD] * mbase[s + 12];
        }
        float acc = (a0 + a1) + (a2 + a3);
        float mv = mbase[tid];
        for (int off = 32; off; off >>= 1) mv += __shfl_down(mv, off);
        if (hl == 0) msum[sg] = mv;
        red[sg][hl] = acc;
        __syncthreads();
        if (sg == 0) {
            float ms = msum[0] + msum[1] + msum[2] + msum[3];
            float len = ms < 1.f ? 1.f : ms;
            hmean[b * HD + h] = (red[0][hl] + red[1][hl] + red[2][hl] + red[3][hl]) / len;
        }
    } else if (bid < 240) {
        // ---- cvtW: W_span[0:2304] -> Wt[n][h] bf16 transposed ----
        float (*tile)[65] = (float(*)[65])smem;
        int idx = bid - 96;
        int hb = idx % 12, rb = (idx / 12) & 3, c = idx / 48;
        for (int e = tid; e < 4096; e += 256) {
            int hl = e >> 6, rl = e & 63;
            tile[hl][rl] = Wspan[(size_t)(c * 768 + hb * 64 + hl) * 256 + rb * 64 + rl];
        }
        __syncthreads();
        for (int e = tid; e < 4096; e += 256) {
            int rl = e >> 6, hl = e & 63;
            Wt[(size_t)(c * 256 + rb * 64 + rl) * 768 + hb * 64 + hl] = f2bf(tile[hl][rl]);
        }
    } else if (bid < 752) {
        // ---- prep: H -> bf16 + logits (4 rows/block, 1 wave each) ----
        int pb = bid - 240;
        int wv = tid >> 6, lane = tid & 63;
        int row = pb * 4 + wv;
        const float4* h4 = (const float4*)(H + (size_t)row * HD);
        const float4* w4 = (const float4*)w_attn;
        float acc = 0.f;
        #pragma unroll
        for (int k = 0; k < 3; ++k) {
            float4 a = h4[k * 64 + lane];
            float4 w = w4[k * 64 + lane];
            acc += a.x * w.x + a.y * w.y + a.z * w.z + a.w * w.w;
            ushort4 o;
            o.x = f2bf(a.x); o.y = f2bf(a.y); o.z = f2bf(a.z); o.w = f2bf(a.w);
            *(ushort4*)(Hb + (size_t)row * HD + k * 256 + lane * 4) = o;
        }
        for (int off = 32; off; off >>= 1) acc += __shfl_down(acc, off);
        if (lane == 0) logits[row] = acc + b_attn[0];
    } else {
        // ---- EW[w][r] ----
        int w = bid - 752;
        int r = tid;
        float acc = 0.f;
        for (int k = 0; k < 32; ++k)
            acc += W_width[w * 32 + k] * Wspan[(size_t)(2304 + k) * RR + r];
        EW[w * RR + r] = acc;
    }
}

// =============== k_mid: GEMM 64x64, 2-phase double-buffered gload_lds | null heads ===============
// T3-minimum pipeline: STAGE(next) issued BEFORE compute(cur); single
// __syncthreads() per K-step (its implicit vmcnt(0) drain lands after the
// loads had the whole compute phase in flight).
// LDS linear dest + inverse-swizzled global source (XOR involution, rule #21).
__global__ __launch_bounds__(256) void k_mid(const ushort* __restrict__ Hb,
                                             const ushort* __restrict__ Wt,
                                             float* __restrict__ P,
                                             const float* __restrict__ hmean,
                                             const float* __restrict__ W_nasp,
                                             const float* __restrict__ b_nasp,
                                             const float* __restrict__ W_nopn,
                                             const float* __restrict__ b_nopn,
                                             float* __restrict__ out_nasp,
                                             float* __restrict__ out_nopn) {
    __shared__ __align__(16) char smem[32768];
    int bid = blockIdx.x;
    int tid = threadIdx.x;

    if (bid < 384) {
        // per buffer: rows 0..63 = A (8 KB), B at +8192; buf stride 16384
        char* lds = smem;
        int mt = bid & 31, nt = bid >> 5;
        int m0 = mt * 64, n0 = nt * 64;
        int wv = tid >> 6, lane = tid & 63;
        int wm = (wv >> 1) * 32, wn = (wv & 1) * 32;

        int ck8 = ((lane & 7) ^ (lane >> 3)) * 8;   // swizzled source chunk (elems)
        int issue0 = wv * 2;
        int srowA = issue0 * 8 + (lane >> 3);       // rows for this wave's 2 issues
        int srowB = srowA + 8;

        auto STAGE = [&](int buf, int k0) {
            char* dst = lds + buf * 16384;
            __builtin_amdgcn_global_load_lds(
                (const __attribute__((address_space(1))) void*)(Hb + (size_t)(m0 + srowA) * HD + k0 + ck8),
                (__attribute__((address_space(3))) void*)(dst + issue0 * 1024), 16, 0, 0);
            __builtin_amdgcn_global_load_lds(
                (const __attribute__((address_space(1))) void*)(Wt + (size_t)(n0 + srowA) * HD + k0 + ck8),
                (__attribute__((address_space(3))) void*)(dst + 8192 + issue0 * 1024), 16, 0, 0);
            __builtin_amdgcn_global_load_lds(
                (const __attribute__((address_space(1))) void*)(Hb + (size_t)(m0 + srowB) * HD + k0 + ck8),
                (__attribute__((address_space(3))) void*)(dst + issue0 * 1024 + 1024), 16, 0, 0);
            __builtin_amdgcn_global_load_lds(
                (const __attribute__((address_space(1))) void*)(Wt + (size_t)(n0 + srowB) * HD + k0 + ck8),
                (__attribute__((address_space(3))) void*)(dst + 8192 + issue0 * 1024 + 1024), 16, 0, 0);
        };

        f32x4 acc[2][2] = {};

        STAGE(0, 0);
        __syncthreads();                       // tile 0 resident
        int cur = 0;
        #pragma unroll 1
        for (int t = 0; t < 12; ++t) {
            if (t + 1 < 12) STAGE(cur ^ 1, (t + 1) * 64);   // prefetch next tile
            char* cb = lds + cur * 16384;
            #pragma unroll
            for (int ks = 0; ks < 2; ++ks) {
                int kb = ks * 64 + ((lane >> 4) * 16);
                bf16x8 af[2], bfr[2];
                #pragma unroll
                for (int f = 0; f < 2; ++f) {
                    int ar = wm + f * 16 + (lane & 15);
                    af[f] = *(const bf16x8*)(cb + ar * 128 + (kb ^ ((ar & 7) << 4)));
                    int br = wn + f * 16 + (lane & 15);
                    bfr[f] = *(const bf16x8*)(cb + 8192 + br * 128 + (kb ^ ((br & 7) << 4)));
                }
                #pragma unroll
                for (int f = 0; f < 2; ++f)
                    #pragma unroll
                    for (int j = 0; j < 2; ++j)
                        acc[f][j] = __builtin_amdgcn_mfma_f32_16x16x32_bf16(af[f], bfr[j], acc[f][j], 0, 0, 0);
            }
            __syncthreads();   // drains vmcnt(0): next tile landed; cur reads done
            cur ^= 1;
        }

        #pragma unroll
        for (int f = 0; f < 2; ++f) {
            #pragma unroll
            for (int j = 0; j < 2; ++j) {
                int col = n0 + wn + j * 16 + (lane & 15);
                size_t pb = (size_t)(col >> 8) * 524288 + (col & 255);
                #pragma unroll
                for (int rg = 0; rg < 4; ++rg) {
                    int row = m0 + wm + f * 16 + (lane >> 4) * 4 + rg;
                    P[pb + (size_t)row * 256] = acc[f][j][rg];
                }
            }
        }
    } else {
        // ---- null heads: 64 blocks ----
        float* hm = (float*)smem;
        float (*ra)[32] = (float(*)[32])(smem + 4096);
        float (*ro)[32] = (float(*)[32])(smem + 5120);
        int idx = bid - 384;
        int b = idx >> 3, rc = idx & 7;
        int c = tid & 31, hc = tid >> 5;
        int r = rc * 32 + c;
        for (int h = tid; h < HD; h += 256) hm[h] = hmean[b * HD + h];
        __syncthreads();
        float a = 0.f, o = 0.f;
        for (int h = hc * 96; h < hc * 96 + 96; ++h) {
            float x = hm[h];
            a += x * W_nasp[(size_t)h * RR + r];
            o += x * W_nopn[(size_t)h * RR + r];
        }
        ra[hc][c] = a; ro[hc][c] = o;
        __syncthreads();
        if (tid < 32) {
            float sa = 0.f, so = 0.f;
            #pragma unroll
            for (int u = 0; u < 8; ++u) { sa += ra[u][tid]; so += ro[u][tid]; }
            int rr = rc * 32 + tid;
            out_nasp[b * RR + rr] = tanhf(sa + b_nasp[rr]);
            out_nopn[b * RR + rr] = tanhf(so + b_nopn[rr]);
        }
    }
}

// =============== k_span4: 1-D grid 2048, XCD-aligned swizzle; float4 per thread ===============
__global__ __launch_bounds__(64) void k_span4(const float* __restrict__ logits,
                                              const float* __restrict__ P,
                                              const float* __restrict__ EW,
                                              const float* __restrict__ b_span,
                                              const float* __restrict__ w_asp,
                                              const float* __restrict__ b_asp,
                                              const float* __restrict__ w_opn,
                                              const float* __restrict__ b_opn,
                                              float* __restrict__ out_repr,
                                              float* __restrict__ out_asp,
                                              float* __restrict__ out_opn) {
    // bijective XCD swizzle (2048 % 8 == 0): XCD x serves batch x's P slice.
    int bid = blockIdx.x;
    int id = (bid & 7) * 256 + (bid >> 3);
    int b = id >> 8;
    int start = id & 255;
    int nw = 256 - start; if (nw > 8) nw = 8;
    int t = threadIdx.x;          // 0..63, cols 4t..4t+3

    int nbase;
    if (start <= 248) nbase = start * 8;
    else { int tt = start - 249; nbase = 1992 + 7 * tt - (tt * (tt - 1)) / 2; }

    float E[8], inv[8];
    {
        float lg[8];
        float M = -INFINITY;
        #pragma unroll
        for (int l = 0; l < 8; ++l) {
            lg[l] = (l < nw) ? logits[b * S + start + l] : -INFINITY;
            M = fmaxf(M, lg[l]);
        }
        float run = 0.f;
        #pragma unroll
        for (int l = 0; l < 8; ++l) {
            E[l] = (l < nw) ? __expf(lg[l] - M) : 0.f;
            run += E[l];
            inv[l] = 1.f / run;
        }
    }

    size_t rb = ((size_t)b * S + start) * 64 + t;
    const f32x4* P04 = (const f32x4*)P;
    const f32x4* P14 = (const f32x4*)(P + 524288);
    const f32x4* P24 = (const f32x4*)(P + 1048576);

    f32x4 p0 = P04[rb];
    f32x4 bs = ((const f32x4*)b_span)[t];
    f32x4 wa = ((const f32x4*)w_asp)[t];
    f32x4 wo = ((const f32x4*)w_opn)[t];
    f32x4 num = {0.f, 0.f, 0.f, 0.f};
    float pa[8], po[8];

    #pragma unroll
    for (int j = 0; j < 8; ++j) {
        // speculative loads for j >= nw stay inside d_ws (safe, unused)
        f32x4 p2 = P24[rb + (size_t)j * 64];
        f32x4 p1 = P14[rb + (size_t)j * 64];
        f32x4 ewj = ((const f32x4*)EW)[(j + 1) * 64 + t];
        num += E[j] * p2;
        f32x4 pre = p0 + p1 + num * inv[j] + ewj + bs;
        f32x4 v;
        v[0] = fmaxf(pre[0], 0.f);
        v[1] = fmaxf(pre[1], 0.f);
        v[2] = fmaxf(pre[2], 0.f);
        v[3] = fmaxf(pre[3], 0.f);
        if (j < nw)
            *(f32x4*)(out_repr + ((size_t)b * NSPAN + nbase + j) * RR + t * 4) = v;
        pa[j] = v[0] * wa[0] + v[1] * wa[1] + v[2] * wa[2] + v[3] * wa[3];
        po[j] = v[0] * wo[0] + v[1] * wo[1] + v[2] * wo[2] + v[3] * wo[3];
    }

    #pragma unroll
    for (int j = 0; j < 8; ++j) {
        if (j < nw) {
            float a = pa[j], o = po[j];
            #pragma unroll
            for (int off = 32; off; off >>= 1) {
                a += __shfl_down(a, off);
                o += __shfl_down(o, off);
            }
            if (t == 0) {
                size_t oi = (size_t)b * NSPAN + nbase + j;
                out_asp[oi] = a + b_asp[0];
                out_opn[oi] = o + b_opn[0];
            }
        }
    }
}

extern "C" void kernel_launch(void* const* d_in, const int* in_sizes, int n_in,
                              void* d_out, int out_size, void* d_ws, size_t ws_size,
                              hipStream_t stream) {
    const float* H       = (const float*)d_in[0];
    const float* mask    = (const float*)d_in[1];
    const float* W_width = (const float*)d_in[2];
    const float* w_attn  = (const float*)d_in[3];
    const float* b_attn  = (const float*)d_in[4];
    const float* W_span  = (const float*)d_in[5];
    const float* b_span  = (const float*)d_in[6];
    const float* w_asp   = (const float*)d_in[7];
    const float* b_asp   = (const float*)d_in[8];
    const float* w_opn   = (const float*)d_in[9];
    const float* b_opn   = (const float*)d_in[10];
    const float* W_nasp  = (const float*)d_in[11];
    const float* b_nasp  = (const float*)d_in[12];
    const float* W_nopn  = (const float*)d_in[13];
    const float* b_nopn  = (const float*)d_in[14];

    float* out  = (float*)d_out;
    float* repr = out;
    float* asp  = out + (size_t)BB * NSPAN * RR;
    float* opn  = asp + (size_t)BB * NSPAN;
    float* nasp = opn + (size_t)BB * NSPAN;
    float* nopn = nasp + (size_t)BB * RR;

    float* ws     = (float*)d_ws;
    float* logits = ws;                 // 2048
    float* hmean  = ws + 2048;          // 6144
    float* EW     = ws + 8192;          // 2304
    float* P      = ws + 10496;         // 3 * 524288 fp32
    ushort* Hb    = (ushort*)(P + 1572864);     // 2048*768 bf16
    ushort* Wt    = Hb + (size_t)2048 * 768;    // 768*768 bf16

    k_pre<<<dim3(761), dim3(256), 0, stream>>>(H, w_attn, b_attn, mask, W_span, W_width,
                                               Hb, logits, Wt, hmean, EW);
    k_mid<<<dim3(448), dim3(256), 0, stream>>>(Hb, Wt, P, hmean,
                                               W_nasp, b_nasp, W_nopn, b_nopn, nasp, nopn);
    k_span4<<<dim3(BB * S), dim3(64), 0, stream>>>(logits, P, EW, b_span, w_asp, b_asp,
                                                   w_opn, b_opn, repr, asp, opn);
}